// Round 16
// baseline (306.823 us; speedup 1.0000x reference)
//
#include <hip/hip_runtime.h>

typedef short short8v __attribute__((ext_vector_type(8)));   // 8 bf16 (4 VGPRs)
typedef float f32x4  __attribute__((ext_vector_type(4)));    // MFMA acc

constexpr float LN_EPS = 1e-5f;

__device__ inline unsigned short f2bf(float f) {
    unsigned u = __float_as_uint(f);
    u += 0x7fffu + ((u >> 16) & 1u);          // RTN-even
    return (unsigned short)(u >> 16);
}
__device__ inline unsigned pack2(float lo, float hi) {
    return (unsigned)f2bf(lo) | ((unsigned)f2bf(hi) << 16);
}
__device__ inline float bflo(unsigned u) { return __uint_as_float(u << 16); }
__device__ inline float bfhi(unsigned u) { return __uint_as_float(u & 0xffff0000u); }

// async global->LDS, 16B per lane
__device__ inline void stage16(const void* gsrc, void* ldst) {
    __builtin_amdgcn_global_load_lds(
        (const __attribute__((address_space(1))) unsigned int*)gsrc,
        (__attribute__((address_space(3))) unsigned int*)ldst,
        16, 0, 0);
}

// ---------------------------------------------------------------------------
// CSR build: degree -> 3-phase device-wide exclusive scan -> bucket fill
// ---------------------------------------------------------------------------
__global__ __launch_bounds__(256)
void degree_kernel(const int* __restrict__ dst, int* __restrict__ deg, int E)
{
    int e = blockIdx.x * 256 + threadIdx.x;
    if (e < E) atomicAdd(&deg[dst[e]], 1);
}

__global__ __launch_bounds__(256)
void scan_local_kernel(const int* __restrict__ deg, int* __restrict__ local,
                       int* __restrict__ blk_sum, int N)
{
    __shared__ int tmp[256];
    const int tid = threadIdx.x;
    const int base = blockIdx.x * 1024 + tid * 4;
    int v0 = (base + 0 < N) ? deg[base + 0] : 0;
    int v1 = (base + 1 < N) ? deg[base + 1] : 0;
    int v2 = (base + 2 < N) ? deg[base + 2] : 0;
    int v3 = (base + 3 < N) ? deg[base + 3] : 0;
    const int s = v0 + v1 + v2 + v3;
    tmp[tid] = s;
    __syncthreads();
    for (int off = 1; off < 256; off <<= 1) {
        int t = (tid >= off) ? tmp[tid - off] : 0;
        __syncthreads();
        tmp[tid] += t;
        __syncthreads();
    }
    int run = tmp[tid] - s;
    if (base + 0 < N) local[base + 0] = run;  run += v0;
    if (base + 1 < N) local[base + 1] = run;  run += v1;
    if (base + 2 < N) local[base + 2] = run;  run += v2;
    if (base + 3 < N) local[base + 3] = run;
    if (tid == 255) blk_sum[blockIdx.x] = tmp[255];
}

__global__ __launch_bounds__(256)
void scan_block_kernel(const int* __restrict__ blk_sum, int* __restrict__ blk_pref,
                       int* __restrict__ total_out, int B)
{
    __shared__ int tmp[256];
    const int tid = threadIdx.x;
    int v = (tid < B) ? blk_sum[tid] : 0;
    tmp[tid] = v;
    __syncthreads();
    for (int off = 1; off < 256; off <<= 1) {
        int t = (tid >= off) ? tmp[tid - off] : 0;
        __syncthreads();
        tmp[tid] += t;
        __syncthreads();
    }
    if (tid < B) blk_pref[tid] = tmp[tid] - v;
    if (tid == 255) *total_out = tmp[255];
}

__global__ __launch_bounds__(256)
void scan_add_kernel(int* __restrict__ row_ptr, int* __restrict__ offs,
                     const int* __restrict__ blk_pref, int N)
{
    const int base = blockIdx.x * 1024 + threadIdx.x * 4;
    const int p = blk_pref[blockIdx.x];
#pragma unroll
    for (int i = 0; i < 4; ++i) {
        int idx = base + i;
        if (idx < N) {
            int val = row_ptr[idx] + p;
            row_ptr[idx] = val;
            offs[idx] = val;
        }
    }
}

__global__ __launch_bounds__(256)
void csr_fill_kernel(const int* __restrict__ src, const int* __restrict__ dst,
                     int* __restrict__ offs, int* __restrict__ csr_src, int E)
{
    int e = blockIdx.x * 256 + threadIdx.x;
    if (e < E) {
        int p = atomicAdd(&offs[dst[e]], 1);
        csr_src[p] = src[e];
    }
}

// ---------------------------------------------------------------------------
// x fp32 -> bf16 into Acat1 cols 128..255
// ---------------------------------------------------------------------------
__global__ __launch_bounds__(256)
void prep_x_kernel(const float* __restrict__ x, unsigned* __restrict__ acat1, int N)
{
    int t = blockIdx.x * 256 + threadIdx.x;
    if (t >= N * 64) return;
    int row = t >> 6, c = t & 63;
    float2 v = ((const float2*)x)[t];
    acat1[(size_t)row * 128 + 64 + c] = pack2(v.x, v.y);
}

// ---------------------------------------------------------------------------
// Pack fp32 weights into MFMA B-fragment layout.
// frag (kt,nt): lane l holds col j = nt*16+(l&15), k = kt*32+(l>>4)*8+e.
// ---------------------------------------------------------------------------
__global__ __launch_bounds__(256)
void pack_w_kernel(const float* __restrict__ WA, int ka,
                   const float* __restrict__ WB, int kb,
                   const float* __restrict__ WC,
                   unsigned short* __restrict__ out, int K)
{
    int t = blockIdx.x * 256 + threadIdx.x;
    int total = (K / 32) * 16 * 64;
    if (t >= total) return;
    int lane = t & 63;
    int nt = (t >> 6) & 15;
    int kt = t >> 10;
    int j = nt * 16 + (lane & 15);
    unsigned short* o = out + (size_t)t * 8;
#pragma unroll
    for (int e = 0; e < 8; ++e) {
        int k = kt * 32 + ((lane >> 4) & 3) * 8 + e;
        float v;
        if (k < ka)      v = WA[(size_t)k * 256 + j];
        else if (k < kb) v = WB[(size_t)(k - ka) * 256 + j];
        else             v = WC[(size_t)(k - kb) * 256 + j];
        o[e] = f2bf(v);
    }
}

// ---------------------------------------------------------------------------
// Gather-mean of x_bf -> Acat1 cols 0..127. Wave/node, 8-way edge unroll.
// ---------------------------------------------------------------------------
__global__ __launch_bounds__(256)
void gather1_kernel(const int* __restrict__ row_ptr, const int* __restrict__ csr_src,
                    unsigned* __restrict__ acat1, int N)
{
    int node = blockIdx.x * 4 + (threadIdx.x >> 6);
    int lane = threadIdx.x & 63;
    if (node >= N) return;
    int beg = row_ptr[node], end = row_ptr[node + 1];
    float a0 = 0.f, a1 = 0.f, b0 = 0.f, b1 = 0.f;
    float c0 = 0.f, c1 = 0.f, d0 = 0.f, d1 = 0.f;
    int e = beg;
    for (; e + 7 < end; e += 8) {
        unsigned u0 = acat1[(size_t)csr_src[e + 0] * 128 + 64 + lane];
        unsigned u1 = acat1[(size_t)csr_src[e + 1] * 128 + 64 + lane];
        unsigned u2 = acat1[(size_t)csr_src[e + 2] * 128 + 64 + lane];
        unsigned u3 = acat1[(size_t)csr_src[e + 3] * 128 + 64 + lane];
        unsigned u4 = acat1[(size_t)csr_src[e + 4] * 128 + 64 + lane];
        unsigned u5 = acat1[(size_t)csr_src[e + 5] * 128 + 64 + lane];
        unsigned u6 = acat1[(size_t)csr_src[e + 6] * 128 + 64 + lane];
        unsigned u7 = acat1[(size_t)csr_src[e + 7] * 128 + 64 + lane];
        a0 += bflo(u0); a1 += bfhi(u0);
        b0 += bflo(u1); b1 += bfhi(u1);
        c0 += bflo(u2); c1 += bfhi(u2);
        d0 += bflo(u3); d1 += bfhi(u3);
        a0 += bflo(u4); a1 += bfhi(u4);
        b0 += bflo(u5); b1 += bfhi(u5);
        c0 += bflo(u6); c1 += bfhi(u6);
        d0 += bflo(u7); d1 += bfhi(u7);
    }
    for (; e + 3 < end; e += 4) {
        unsigned u0 = acat1[(size_t)csr_src[e + 0] * 128 + 64 + lane];
        unsigned u1 = acat1[(size_t)csr_src[e + 1] * 128 + 64 + lane];
        unsigned u2 = acat1[(size_t)csr_src[e + 2] * 128 + 64 + lane];
        unsigned u3 = acat1[(size_t)csr_src[e + 3] * 128 + 64 + lane];
        a0 += bflo(u0); a1 += bfhi(u0);
        b0 += bflo(u1); b1 += bfhi(u1);
        c0 += bflo(u2); c1 += bfhi(u2);
        d0 += bflo(u3); d1 += bfhi(u3);
    }
    for (; e < end; ++e) {
        unsigned u = acat1[(size_t)csr_src[e] * 128 + 64 + lane];
        a0 += bflo(u); a1 += bfhi(u);
    }
    a0 += b0 + c0 + d0; a1 += b1 + c1 + d1;
    float inv = 1.0f / fmaxf((float)(end - beg), 1.0f);
    acat1[(size_t)node * 128 + lane] = pack2(a0 * inv, a1 * inv);
}

// ---------------------------------------------------------------------------
// Gather-mean of h1_bf -> Acat2 cols 0..255. Wave/node, uint2, 8-way unroll.
// ---------------------------------------------------------------------------
__global__ __launch_bounds__(256)
void gather2_kernel(const int* __restrict__ row_ptr, const int* __restrict__ csr_src,
                    unsigned* __restrict__ acat2, int N)
{
    int node = blockIdx.x * 4 + (threadIdx.x >> 6);
    int lane = threadIdx.x & 63;
    if (node >= N) return;
    int beg = row_ptr[node], end = row_ptr[node + 1];
    float a0 = 0.f, a1 = 0.f, a2 = 0.f, a3 = 0.f;
    float b0 = 0.f, b1 = 0.f, b2 = 0.f, b3 = 0.f;
    float c0 = 0.f, c1 = 0.f, c2 = 0.f, c3 = 0.f;
    float d0 = 0.f, d1 = 0.f, d2 = 0.f, d3 = 0.f;
    int e = beg;
    for (; e + 7 < end; e += 8) {
        const uint2 u0 = *(const uint2*)(acat2 + (size_t)csr_src[e + 0] * 256 + 128 + lane * 2);
        const uint2 u1 = *(const uint2*)(acat2 + (size_t)csr_src[e + 1] * 256 + 128 + lane * 2);
        const uint2 u2 = *(const uint2*)(acat2 + (size_t)csr_src[e + 2] * 256 + 128 + lane * 2);
        const uint2 u3 = *(const uint2*)(acat2 + (size_t)csr_src[e + 3] * 256 + 128 + lane * 2);
        const uint2 u4 = *(const uint2*)(acat2 + (size_t)csr_src[e + 4] * 256 + 128 + lane * 2);
        const uint2 u5 = *(const uint2*)(acat2 + (size_t)csr_src[e + 5] * 256 + 128 + lane * 2);
        const uint2 u6 = *(const uint2*)(acat2 + (size_t)csr_src[e + 6] * 256 + 128 + lane * 2);
        const uint2 u7 = *(const uint2*)(acat2 + (size_t)csr_src[e + 7] * 256 + 128 + lane * 2);
        a0 += bflo(u0.x); a1 += bfhi(u0.x); a2 += bflo(u0.y); a3 += bfhi(u0.y);
        b0 += bflo(u1.x); b1 += bfhi(u1.x); b2 += bflo(u1.y); b3 += bfhi(u1.y);
        c0 += bflo(u2.x); c1 += bfhi(u2.x); c2 += bflo(u2.y); c3 += bfhi(u2.y);
        d0 += bflo(u3.x); d1 += bfhi(u3.x); d2 += bflo(u3.y); d3 += bfhi(u3.y);
        a0 += bflo(u4.x); a1 += bfhi(u4.x); a2 += bflo(u4.y); a3 += bfhi(u4.y);
        b0 += bflo(u5.x); b1 += bfhi(u5.x); b2 += bflo(u5.y); b3 += bfhi(u5.y);
        c0 += bflo(u6.x); c1 += bfhi(u6.x); c2 += bflo(u6.y); c3 += bfhi(u6.y);
        d0 += bflo(u7.x); d1 += bfhi(u7.x); d2 += bflo(u7.y); d3 += bfhi(u7.y);
    }
    for (; e + 3 < end; e += 4) {
        const uint2 u0 = *(const uint2*)(acat2 + (size_t)csr_src[e + 0] * 256 + 128 + lane * 2);
        const uint2 u1 = *(const uint2*)(acat2 + (size_t)csr_src[e + 1] * 256 + 128 + lane * 2);
        const uint2 u2 = *(const uint2*)(acat2 + (size_t)csr_src[e + 2] * 256 + 128 + lane * 2);
        const uint2 u3 = *(const uint2*)(acat2 + (size_t)csr_src[e + 3] * 256 + 128 + lane * 2);
        a0 += bflo(u0.x); a1 += bfhi(u0.x); a2 += bflo(u0.y); a3 += bfhi(u0.y);
        b0 += bflo(u1.x); b1 += bfhi(u1.x); b2 += bflo(u1.y); b3 += bfhi(u1.y);
        c0 += bflo(u2.x); c1 += bfhi(u2.x); c2 += bflo(u2.y); c3 += bfhi(u2.y);
        d0 += bflo(u3.x); d1 += bfhi(u3.x); d2 += bflo(u3.y); d3 += bfhi(u3.y);
    }
    for (; e < end; ++e) {
        const uint2 u = *(const uint2*)(acat2 + (size_t)csr_src[e] * 256 + 128 + lane * 2);
        a0 += bflo(u.x); a1 += bfhi(u.x); a2 += bflo(u.y); a3 += bfhi(u.y);
    }
    a0 += b0 + c0 + d0; a1 += b1 + c1 + d1;
    a2 += b2 + c2 + d2; a3 += b3 + c3 + d3;
    float inv = 1.0f / fmaxf((float)(end - beg), 1.0f);
    uint2 o;
    o.x = pack2(a0 * inv, a1 * inv);
    o.y = pack2(a2 * inv, a3 * inv);
    *(uint2*)(acat2 + (size_t)node * 256 + lane * 2) = o;
}

// stage one 16KB kt-tile: 256 threads x 16B x 4
#define STAGE_KT(kt_, buf_)                                                     \
    {                                                                           \
        const char* s_ = bsrc + (size_t)(kt_) * 16384;                          \
        char* d_ = (char*)&bbuf[buf_][0][0];                                    \
        _Pragma("unroll")                                                       \
        for (int i_ = 0; i_ < 4; ++i_)                                          \
            stage16(s_ + i_ * 4096 + tid * 16, d_ + i_ * 4096 + tid * 16);      \
    }

// ---------------------------------------------------------------------------
// GEMM1: h1 = relu(LN(Acat1[N,256] @ W1 + bl)) -> bf16 into Acat2 cols 256..511
// 32 rows/block, 4-wave col-split (wave owns 64 cols, 2 row-groups).
// B double-buffered in LDS via global_load_lds + per-kt __syncthreads
// (r14 sync discipline x r6 geometry; grid = N/32 = 1563 fills the CUs).
// ---------------------------------------------------------------------------
__global__ __launch_bounds__(256, 4)
void gemm1_kernel(const short8v* __restrict__ A,     // Acat1: 32 frags per row
                  const unsigned short* __restrict__ Bpk,  // Wpk1: 8 kt * 16KB
                  const float* __restrict__ bl, const float* __restrict__ g,
                  const float* __restrict__ be,
                  unsigned short* __restrict__ h1out, // Acat2 ushort view, stride 512
                  int N)
{
    __shared__ short8v bbuf[2][16][64];               // 2 x 16KB
    __shared__ float sS[4][32], sSS[4][32];
    const int tid  = threadIdx.x;
    const int lane = tid & 63;
    const int wave = tid >> 6;
    const int rbase = blockIdx.x * 32;
    int ar0 = rbase + (lane & 15);
    int ar1 = ar0 + 16;
    if (ar0 >= N) ar0 = N - 1;
    if (ar1 >= N) ar1 = N - 1;
    const short8v* Ar0 = A + (size_t)ar0 * 32 + (lane >> 4);
    const short8v* Ar1 = A + (size_t)ar1 * 32 + (lane >> 4);
    const char* bsrc = (const char*)Bpk;

    STAGE_KT(0, 0);

    f32x4 acc[2][4];
#pragma unroll
    for (int rg = 0; rg < 2; ++rg)
#pragma unroll
        for (int nt = 0; nt < 4; ++nt) acc[rg][nt] = (f32x4){0.f, 0.f, 0.f, 0.f};

    short8v a0 = Ar0[0], a1 = Ar1[0], an0 = a0, an1 = a1;
    __syncthreads();

#pragma unroll
    for (int kt = 0; kt < 8; ++kt) {
        if (kt + 1 < 8) {
            STAGE_KT(kt + 1, (kt + 1) & 1);
            an0 = Ar0[(kt + 1) * 4];
            an1 = Ar1[(kt + 1) * 4];
        }
#pragma unroll
        for (int ntl = 0; ntl < 4; ++ntl) {
            short8v b = bbuf[kt & 1][wave * 4 + ntl][lane];
            acc[0][ntl] = __builtin_amdgcn_mfma_f32_16x16x32_bf16(a0, b, acc[0][ntl], 0, 0, 0);
            acc[1][ntl] = __builtin_amdgcn_mfma_f32_16x16x32_bf16(a1, b, acc[1][ntl], 0, 0, 0);
        }
        __syncthreads();
        a0 = an0; a1 = an1;
    }

    // epilogue: bias, cross-wave LN (both row-groups), relu, bf16 store
    const int col0 = lane & 15;
    const int grp  = lane >> 4;
    float s[2][4] = {{0,0,0,0},{0,0,0,0}}, ss[2][4] = {{0,0,0,0},{0,0,0,0}};
#pragma unroll
    for (int nt = 0; nt < 4; ++nt) {
        float blv = bl[(wave * 4 + nt) * 16 + col0];
#pragma unroll
        for (int rg = 0; rg < 2; ++rg)
#pragma unroll
            for (int r = 0; r < 4; ++r) {
                float v = acc[rg][nt][r] + blv;
                acc[rg][nt][r] = v;
                s[rg][r] += v; ss[rg][r] += v * v;
            }
    }
#pragma unroll
    for (int off = 1; off < 16; off <<= 1) {
#pragma unroll
        for (int rg = 0; rg < 2; ++rg)
#pragma unroll
            for (int r = 0; r < 4; ++r) {
                s[rg][r]  += __shfl_xor(s[rg][r],  off);
                ss[rg][r] += __shfl_xor(ss[rg][r], off);
            }
    }
    if (col0 == 0) {
#pragma unroll
        for (int rg = 0; rg < 2; ++rg)
#pragma unroll
            for (int r = 0; r < 4; ++r) {
                sS[wave][rg * 16 + grp * 4 + r]  = s[rg][r];
                sSS[wave][rg * 16 + grp * 4 + r] = ss[rg][r];
            }
    }
    __syncthreads();
    float mu[2][4], inv[2][4];
#pragma unroll
    for (int rg = 0; rg < 2; ++rg)
#pragma unroll
        for (int r = 0; r < 4; ++r) {
            int row = rg * 16 + grp * 4 + r;
            float S  = sS[0][row] + sS[1][row] + sS[2][row] + sS[3][row];
            float SS = sSS[0][row] + sSS[1][row] + sSS[2][row] + sSS[3][row];
            mu[rg][r] = S * (1.f / 256.f);
            float var = SS * (1.f / 256.f) - mu[rg][r] * mu[rg][r];
            inv[rg][r] = rsqrtf(var + LN_EPS);
        }
#pragma unroll
    for (int nt = 0; nt < 4; ++nt) {
        int col = (wave * 4 + nt) * 16 + col0;
        float gv = g[col], bv = be[col];
#pragma unroll
        for (int rg = 0; rg < 2; ++rg)
#pragma unroll
            for (int r = 0; r < 4; ++r) {
                int srow = rbase + rg * 16 + grp * 4 + r;
                if (srow < N) {
                    float v = (acc[rg][nt][r] - mu[rg][r]) * inv[rg][r] * gv + bv;
                    h1out[(size_t)srow * 512 + 256 + col] = f2bf(fmaxf(v, 0.f));
                }
            }
    }
}

// ---------------------------------------------------------------------------
// GEMM2: out = relu(LN(Acat2[N,512] @ W2 + bl2)) + (x_bf @ Wres + bres)
// Same geometry/sync, 20 kt. Cross-wave LN->relu transform at kt==16;
// residual GEMM (kt 16..19) accumulates via MFMA C-in.
// ---------------------------------------------------------------------------
__global__ __launch_bounds__(256, 4)
void gemm2_kernel(const short8v* __restrict__ A2,    // Acat2: 64 frags per row
                  const short8v* __restrict__ A1,    // Acat1: 32 frags per row
                  const unsigned short* __restrict__ Bpk,  // Wpk2: 20 kt * 16KB
                  const float* __restrict__ bl, const float* __restrict__ g,
                  const float* __restrict__ be, const float* __restrict__ bres,
                  float* __restrict__ out, int N)
{
    __shared__ short8v bbuf[2][16][64];               // 2 x 16KB
    __shared__ float sS[4][32], sSS[4][32];
    const int tid  = threadIdx.x;
    const int lane = tid & 63;
    const int wave = tid >> 6;
    const int rbase = blockIdx.x * 32;
    int ar0 = rbase + (lane & 15);
    int ar1 = ar0 + 16;
    if (ar0 >= N) ar0 = N - 1;
    if (ar1 >= N) ar1 = N - 1;
    const short8v* Ar2_0 = A2 + (size_t)ar0 * 64 + (lane >> 4);
    const short8v* Ar2_1 = A2 + (size_t)ar1 * 64 + (lane >> 4);
    const short8v* Ar1_0 = A1 + (size_t)ar0 * 32 + 16 + (lane >> 4);
    const short8v* Ar1_1 = A1 + (size_t)ar1 * 32 + 16 + (lane >> 4);
    const char* bsrc = (const char*)Bpk;

    STAGE_KT(0, 0);

    f32x4 acc[2][4];
#pragma unroll
    for (int rg = 0; rg < 2; ++rg)
#pragma unroll
        for (int nt = 0; nt < 4; ++nt) acc[rg][nt] = (f32x4){0.f, 0.f, 0.f, 0.f};

    const int col0 = lane & 15;
    const int grp  = lane >> 4;

    short8v a0 = Ar2_0[0], a1 = Ar2_1[0], an0 = a0, an1 = a1;
    __syncthreads();

#pragma unroll
    for (int kt = 0; kt < 20; ++kt) {
        if (kt + 1 < 20) {
            STAGE_KT(kt + 1, (kt + 1) & 1);
            if (kt + 1 < 16) { an0 = Ar2_0[(kt + 1) * 4]; an1 = Ar2_1[(kt + 1) * 4]; }
            else             { an0 = Ar1_0[(kt + 1 - 16) * 4]; an1 = Ar1_1[(kt + 1 - 16) * 4]; }
        }

        if (kt == 16) {
            // acc <- relu(LN(acc + bl)) with cross-wave reduce (acc = kt0..15 sum)
            float s[2][4] = {{0,0,0,0},{0,0,0,0}}, ss[2][4] = {{0,0,0,0},{0,0,0,0}};
#pragma unroll
            for (int nt = 0; nt < 4; ++nt) {
                float blv = bl[(wave * 4 + nt) * 16 + col0];
#pragma unroll
                for (int rg = 0; rg < 2; ++rg)
#pragma unroll
                    for (int r = 0; r < 4; ++r) {
                        float v = acc[rg][nt][r] + blv;
                        acc[rg][nt][r] = v;
                        s[rg][r] += v; ss[rg][r] += v * v;
                    }
            }
#pragma unroll
            for (int off = 1; off < 16; off <<= 1) {
#pragma unroll
                for (int rg = 0; rg < 2; ++rg)
#pragma unroll
                    for (int r = 0; r < 4; ++r) {
                        s[rg][r]  += __shfl_xor(s[rg][r],  off);
                        ss[rg][r] += __shfl_xor(ss[rg][r], off);
                    }
            }
            if (col0 == 0) {
#pragma unroll
                for (int rg = 0; rg < 2; ++rg)
#pragma unroll
                    for (int r = 0; r < 4; ++r) {
                        sS[wave][rg * 16 + grp * 4 + r]  = s[rg][r];
                        sSS[wave][rg * 16 + grp * 4 + r] = ss[rg][r];
                    }
            }
            __syncthreads();
#pragma unroll
            for (int rg = 0; rg < 2; ++rg)
#pragma unroll
                for (int r = 0; r < 4; ++r) {
                    int row = rg * 16 + grp * 4 + r;
                    float S  = sS[0][row] + sS[1][row] + sS[2][row] + sS[3][row];
                    float SS = sSS[0][row] + sSS[1][row] + sSS[2][row] + sSS[3][row];
                    float mu = S * (1.f / 256.f);
                    float var = SS * (1.f / 256.f) - mu * mu;
                    float invs = rsqrtf(var + LN_EPS);
#pragma unroll
                    for (int nt = 0; nt < 4; ++nt) {
                        int col = (wave * 4 + nt) * 16 + col0;
                        float v = (acc[rg][nt][r] - mu) * invs * g[col] + be[col];
                        acc[rg][nt][r] = fmaxf(v, 0.f);
                    }
                }
        }

#pragma unroll
        for (int ntl = 0; ntl < 4; ++ntl) {
            short8v b = bbuf[kt & 1][wave * 4 + ntl][lane];
            acc[0][ntl] = __builtin_amdgcn_mfma_f32_16x16x32_bf16(a0, b, acc[0][ntl], 0, 0, 0);
            acc[1][ntl] = __builtin_amdgcn_mfma_f32_16x16x32_bf16(a1, b, acc[1][ntl], 0, 0, 0);
        }
        __syncthreads();
        a0 = an0; a1 = an1;
    }

#pragma unroll
    for (int nt = 0; nt < 4; ++nt) {
        int col = (wave * 4 + nt) * 16 + col0;
        float brv = bres[col];
#pragma unroll
        for (int rg = 0; rg < 2; ++rg)
#pragma unroll
            for (int r = 0; r < 4; ++r) {
                int srow = rbase + rg * 16 + grp * 4 + r;
                if (srow < N)
                    out[(size_t)srow * 256 + col] = acc[rg][nt][r] + brv;
            }
    }
}

extern "C" void kernel_launch(void* const* d_in, const int* in_sizes, int n_in,
                              void* d_out, int out_size, void* d_ws, size_t ws_size,
                              hipStream_t stream)
{
    const float* x    = (const float*)d_in[0];
    const int*   ei   = (const int*)d_in[1];
    const float* Wl1  = (const float*)d_in[2];
    const float* bl1  = (const float*)d_in[3];
    const float* Wr1  = (const float*)d_in[4];
    const float* g1   = (const float*)d_in[5];
    const float* be1  = (const float*)d_in[6];
    const float* Wl2  = (const float*)d_in[7];
    const float* bl2  = (const float*)d_in[8];
    const float* Wr2  = (const float*)d_in[9];
    const float* g2   = (const float*)d_in[10];
    const float* be2  = (const float*)d_in[11];
    const float* Wres = (const float*)d_in[12];
    const float* bres = (const float*)d_in[13];

    const int N = in_sizes[0] / 128;
    const int E = in_sizes[1] / 2;
    const int* src = ei;
    const int* dst = ei + E;

    // ws layout: Acat1 N*256 bf16 | Acat2 N*512 bf16 | Wpk1 256*256 bf16
    //            | Wpk2 640*256 bf16 | deg N | row_ptr N+1 | offs N | csr_src E
    //            | blk_sum 256 | blk_pref 256
    unsigned short* acat1 = (unsigned short*)d_ws;
    unsigned short* acat2 = acat1 + (size_t)N * 256;
    unsigned short* wpk1  = acat2 + (size_t)N * 512;
    unsigned short* wpk2  = wpk1 + 256 * 256;
    int* deg      = (int*)(wpk2 + 640 * 256);
    int* row_ptr  = deg + N;
    int* offs     = row_ptr + (N + 1);
    int* csr_src  = offs + N;
    int* blk_sum  = csr_src + E;
    int* blk_pref = blk_sum + 256;

    hipMemsetAsync(deg, 0, (size_t)N * sizeof(int), stream);

    const int eb = (E + 255) / 256;
    const int sb = (N + 1023) / 1024;
    degree_kernel<<<eb, 256, 0, stream>>>(dst, deg, E);
    scan_local_kernel<<<sb, 256, 0, stream>>>(deg, row_ptr, blk_sum, N);
    scan_block_kernel<<<1, 256, 0, stream>>>(blk_sum, blk_pref, row_ptr + N, sb);
    scan_add_kernel<<<sb, 256, 0, stream>>>(row_ptr, offs, blk_pref, N);
    csr_fill_kernel<<<eb, 256, 0, stream>>>(src, dst, offs, csr_src, E);

    prep_x_kernel<<<(N * 64 + 255) / 256, 256, 0, stream>>>(x, (unsigned*)acat1, N);
    pack_w_kernel<<<(8 * 16 * 64 + 255) / 256, 256, 0, stream>>>(Wl1, 128, Wr1, 256, Wr1, wpk1, 256);
    pack_w_kernel<<<(20 * 16 * 64 + 255) / 256, 256, 0, stream>>>(Wl2, 256, Wr2, 512, Wres, wpk2, 640);

    gather1_kernel<<<(N + 3) / 4, 256, 0, stream>>>(row_ptr, csr_src, (unsigned*)acat1, N);

    const int gb = (N + 31) / 32;
    gemm1_kernel<<<gb, 256, 0, stream>>>((const short8v*)acat1, wpk1,
                                         bl1, g1, be1, acat2, N);

    gather2_kernel<<<(N + 3) / 4, 256, 0, stream>>>(row_ptr, csr_src, (unsigned*)acat2, N);

    gemm2_kernel<<<gb, 256, 0, stream>>>((const short8v*)acat2, (const short8v*)acat1,
                                         wpk2, bl2, g2, be2, bres,
                                         (float*)d_out, N);
}

// Round 18
// 281.044 us; speedup vs baseline: 1.0917x; 1.0917x over previous
//
#include <hip/hip_runtime.h>

typedef short short8v __attribute__((ext_vector_type(8)));   // 8 bf16 (4 VGPRs)
typedef float f32x4  __attribute__((ext_vector_type(4)));    // MFMA acc

constexpr float LN_EPS = 1e-5f;

__device__ inline unsigned short f2bf(float f) {
    unsigned u = __float_as_uint(f);
    u += 0x7fffu + ((u >> 16) & 1u);          // RTN-even
    return (unsigned short)(u >> 16);
}
__device__ inline unsigned pack2(float lo, float hi) {
    return (unsigned)f2bf(lo) | ((unsigned)f2bf(hi) << 16);
}
__device__ inline float bflo(unsigned u) { return __uint_as_float(u << 16); }
__device__ inline float bfhi(unsigned u) { return __uint_as_float(u & 0xffff0000u); }

// async global->LDS, 16B per lane (dest = wave-uniform base + lane*16)
__device__ inline void stage16(const void* gsrc, void* ldst) {
    __builtin_amdgcn_global_load_lds(
        (const __attribute__((address_space(1))) unsigned int*)gsrc,
        (__attribute__((address_space(3))) unsigned int*)ldst,
        16, 0, 0);
}

// ---------------------------------------------------------------------------
// CSR build: degree -> 3-phase device-wide exclusive scan -> bucket fill
// ---------------------------------------------------------------------------
__global__ __launch_bounds__(256)
void degree_kernel(const int* __restrict__ dst, int* __restrict__ deg, int E)
{
    int e = blockIdx.x * 256 + threadIdx.x;
    if (e < E) atomicAdd(&deg[dst[e]], 1);
}

__global__ __launch_bounds__(256)
void scan_local_kernel(const int* __restrict__ deg, int* __restrict__ local,
                       int* __restrict__ blk_sum, int N)
{
    __shared__ int tmp[256];
    const int tid = threadIdx.x;
    const int base = blockIdx.x * 1024 + tid * 4;
    int v0 = (base + 0 < N) ? deg[base + 0] : 0;
    int v1 = (base + 1 < N) ? deg[base + 1] : 0;
    int v2 = (base + 2 < N) ? deg[base + 2] : 0;
    int v3 = (base + 3 < N) ? deg[base + 3] : 0;
    const int s = v0 + v1 + v2 + v3;
    tmp[tid] = s;
    __syncthreads();
    for (int off = 1; off < 256; off <<= 1) {
        int t = (tid >= off) ? tmp[tid - off] : 0;
        __syncthreads();
        tmp[tid] += t;
        __syncthreads();
    }
    int run = tmp[tid] - s;
    if (base + 0 < N) local[base + 0] = run;  run += v0;
    if (base + 1 < N) local[base + 1] = run;  run += v1;
    if (base + 2 < N) local[base + 2] = run;  run += v2;
    if (base + 3 < N) local[base + 3] = run;
    if (tid == 255) blk_sum[blockIdx.x] = tmp[255];
}

__global__ __launch_bounds__(256)
void scan_block_kernel(const int* __restrict__ blk_sum, int* __restrict__ blk_pref,
                       int* __restrict__ total_out, int B)
{
    __shared__ int tmp[256];
    const int tid = threadIdx.x;
    int v = (tid < B) ? blk_sum[tid] : 0;
    tmp[tid] = v;
    __syncthreads();
    for (int off = 1; off < 256; off <<= 1) {
        int t = (tid >= off) ? tmp[tid - off] : 0;
        __syncthreads();
        tmp[tid] += t;
        __syncthreads();
    }
    if (tid < B) blk_pref[tid] = tmp[tid] - v;
    if (tid == 255) *total_out = tmp[255];
}

__global__ __launch_bounds__(256)
void scan_add_kernel(int* __restrict__ row_ptr, int* __restrict__ offs,
                     const int* __restrict__ blk_pref, int N)
{
    const int base = blockIdx.x * 1024 + threadIdx.x * 4;
    const int p = blk_pref[blockIdx.x];
#pragma unroll
    for (int i = 0; i < 4; ++i) {
        int idx = base + i;
        if (idx < N) {
            int val = row_ptr[idx] + p;
            row_ptr[idx] = val;
            offs[idx] = val;
        }
    }
}

__global__ __launch_bounds__(256)
void csr_fill_kernel(const int* __restrict__ src, const int* __restrict__ dst,
                     int* __restrict__ offs, int* __restrict__ csr_src, int E)
{
    int e = blockIdx.x * 256 + threadIdx.x;
    if (e < E) {
        int p = atomicAdd(&offs[dst[e]], 1);
        csr_src[p] = src[e];
    }
}

// ---------------------------------------------------------------------------
// x fp32 -> bf16 into Acat1 cols 128..255
// ---------------------------------------------------------------------------
__global__ __launch_bounds__(256)
void prep_x_kernel(const float* __restrict__ x, unsigned* __restrict__ acat1, int N)
{
    int t = blockIdx.x * 256 + threadIdx.x;
    if (t >= N * 64) return;
    int row = t >> 6, c = t & 63;
    float2 v = ((const float2*)x)[t];
    acat1[(size_t)row * 128 + 64 + c] = pack2(v.x, v.y);
}

// ---------------------------------------------------------------------------
// Pack fp32 weights into MFMA B-fragment layout.
// frag (kt,nt): lane l holds col j = nt*16+(l&15), k = kt*32+(l>>4)*8+e.
// ---------------------------------------------------------------------------
__global__ __launch_bounds__(256)
void pack_w_kernel(const float* __restrict__ WA, int ka,
                   const float* __restrict__ WB, int kb,
                   const float* __restrict__ WC,
                   unsigned short* __restrict__ out, int K)
{
    int t = blockIdx.x * 256 + threadIdx.x;
    int total = (K / 32) * 16 * 64;
    if (t >= total) return;
    int lane = t & 63;
    int nt = (t >> 6) & 15;
    int kt = t >> 10;
    int j = nt * 16 + (lane & 15);
    unsigned short* o = out + (size_t)t * 8;
#pragma unroll
    for (int e = 0; e < 8; ++e) {
        int k = kt * 32 + ((lane >> 4) & 3) * 8 + e;
        float v;
        if (k < ka)      v = WA[(size_t)k * 256 + j];
        else if (k < kb) v = WB[(size_t)(k - ka) * 256 + j];
        else             v = WC[(size_t)(k - kb) * 256 + j];
        o[e] = f2bf(v);
    }
}

// ---------------------------------------------------------------------------
// Gather-mean of x_bf -> Acat1 cols 0..127. Wave/node, 8-way edge unroll.
// ---------------------------------------------------------------------------
__global__ __launch_bounds__(256)
void gather1_kernel(const int* __restrict__ row_ptr, const int* __restrict__ csr_src,
                    unsigned* __restrict__ acat1, int N)
{
    int node = blockIdx.x * 4 + (threadIdx.x >> 6);
    int lane = threadIdx.x & 63;
    if (node >= N) return;
    int beg = row_ptr[node], end = row_ptr[node + 1];
    float a0 = 0.f, a1 = 0.f, b0 = 0.f, b1 = 0.f;
    float c0 = 0.f, c1 = 0.f, d0 = 0.f, d1 = 0.f;
    int e = beg;
    for (; e + 7 < end; e += 8) {
        unsigned u0 = acat1[(size_t)csr_src[e + 0] * 128 + 64 + lane];
        unsigned u1 = acat1[(size_t)csr_src[e + 1] * 128 + 64 + lane];
        unsigned u2 = acat1[(size_t)csr_src[e + 2] * 128 + 64 + lane];
        unsigned u3 = acat1[(size_t)csr_src[e + 3] * 128 + 64 + lane];
        unsigned u4 = acat1[(size_t)csr_src[e + 4] * 128 + 64 + lane];
        unsigned u5 = acat1[(size_t)csr_src[e + 5] * 128 + 64 + lane];
        unsigned u6 = acat1[(size_t)csr_src[e + 6] * 128 + 64 + lane];
        unsigned u7 = acat1[(size_t)csr_src[e + 7] * 128 + 64 + lane];
        a0 += bflo(u0); a1 += bfhi(u0);
        b0 += bflo(u1); b1 += bfhi(u1);
        c0 += bflo(u2); c1 += bfhi(u2);
        d0 += bflo(u3); d1 += bfhi(u3);
        a0 += bflo(u4); a1 += bfhi(u4);
        b0 += bflo(u5); b1 += bfhi(u5);
        c0 += bflo(u6); c1 += bfhi(u6);
        d0 += bflo(u7); d1 += bfhi(u7);
    }
    for (; e + 3 < end; e += 4) {
        unsigned u0 = acat1[(size_t)csr_src[e + 0] * 128 + 64 + lane];
        unsigned u1 = acat1[(size_t)csr_src[e + 1] * 128 + 64 + lane];
        unsigned u2 = acat1[(size_t)csr_src[e + 2] * 128 + 64 + lane];
        unsigned u3 = acat1[(size_t)csr_src[e + 3] * 128 + 64 + lane];
        a0 += bflo(u0); a1 += bfhi(u0);
        b0 += bflo(u1); b1 += bfhi(u1);
        c0 += bflo(u2); c1 += bfhi(u2);
        d0 += bflo(u3); d1 += bfhi(u3);
    }
    for (; e < end; ++e) {
        unsigned u = acat1[(size_t)csr_src[e] * 128 + 64 + lane];
        a0 += bflo(u); a1 += bfhi(u);
    }
    a0 += b0 + c0 + d0; a1 += b1 + c1 + d1;
    float inv = 1.0f / fmaxf((float)(end - beg), 1.0f);
    acat1[(size_t)node * 128 + lane] = pack2(a0 * inv, a1 * inv);
}

// ---------------------------------------------------------------------------
// Gather-mean of h1_bf -> Acat2 cols 0..255. Wave/node, uint2, 8-way unroll.
// ---------------------------------------------------------------------------
__global__ __launch_bounds__(256)
void gather2_kernel(const int* __restrict__ row_ptr, const int* __restrict__ csr_src,
                    unsigned* __restrict__ acat2, int N)
{
    int node = blockIdx.x * 4 + (threadIdx.x >> 6);
    int lane = threadIdx.x & 63;
    if (node >= N) return;
    int beg = row_ptr[node], end = row_ptr[node + 1];
    float a0 = 0.f, a1 = 0.f, a2 = 0.f, a3 = 0.f;
    float b0 = 0.f, b1 = 0.f, b2 = 0.f, b3 = 0.f;
    float c0 = 0.f, c1 = 0.f, c2 = 0.f, c3 = 0.f;
    float d0 = 0.f, d1 = 0.f, d2 = 0.f, d3 = 0.f;
    int e = beg;
    for (; e + 7 < end; e += 8) {
        const uint2 u0 = *(const uint2*)(acat2 + (size_t)csr_src[e + 0] * 256 + 128 + lane * 2);
        const uint2 u1 = *(const uint2*)(acat2 + (size_t)csr_src[e + 1] * 256 + 128 + lane * 2);
        const uint2 u2 = *(const uint2*)(acat2 + (size_t)csr_src[e + 2] * 256 + 128 + lane * 2);
        const uint2 u3 = *(const uint2*)(acat2 + (size_t)csr_src[e + 3] * 256 + 128 + lane * 2);
        const uint2 u4 = *(const uint2*)(acat2 + (size_t)csr_src[e + 4] * 256 + 128 + lane * 2);
        const uint2 u5 = *(const uint2*)(acat2 + (size_t)csr_src[e + 5] * 256 + 128 + lane * 2);
        const uint2 u6 = *(const uint2*)(acat2 + (size_t)csr_src[e + 6] * 256 + 128 + lane * 2);
        const uint2 u7 = *(const uint2*)(acat2 + (size_t)csr_src[e + 7] * 256 + 128 + lane * 2);
        a0 += bflo(u0.x); a1 += bfhi(u0.x); a2 += bflo(u0.y); a3 += bfhi(u0.y);
        b0 += bflo(u1.x); b1 += bfhi(u1.x); b2 += bflo(u1.y); b3 += bfhi(u1.y);
        c0 += bflo(u2.x); c1 += bfhi(u2.x); c2 += bflo(u2.y); c3 += bfhi(u2.y);
        d0 += bflo(u3.x); d1 += bfhi(u3.x); d2 += bflo(u3.y); d3 += bfhi(u3.y);
        a0 += bflo(u4.x); a1 += bfhi(u4.x); a2 += bflo(u4.y); a3 += bfhi(u4.y);
        b0 += bflo(u5.x); b1 += bfhi(u5.x); b2 += bflo(u5.y); b3 += bfhi(u5.y);
        c0 += bflo(u6.x); c1 += bfhi(u6.x); c2 += bflo(u6.y); c3 += bfhi(u6.y);
        d0 += bflo(u7.x); d1 += bfhi(u7.x); d2 += bflo(u7.y); d3 += bfhi(u7.y);
    }
    for (; e + 3 < end; e += 4) {
        const uint2 u0 = *(const uint2*)(acat2 + (size_t)csr_src[e + 0] * 256 + 128 + lane * 2);
        const uint2 u1 = *(const uint2*)(acat2 + (size_t)csr_src[e + 1] * 256 + 128 + lane * 2);
        const uint2 u2 = *(const uint2*)(acat2 + (size_t)csr_src[e + 2] * 256 + 128 + lane * 2);
        const uint2 u3 = *(const uint2*)(acat2 + (size_t)csr_src[e + 3] * 256 + 128 + lane * 2);
        a0 += bflo(u0.x); a1 += bfhi(u0.x); a2 += bflo(u0.y); a3 += bfhi(u0.y);
        b0 += bflo(u1.x); b1 += bfhi(u1.x); b2 += bflo(u1.y); b3 += bfhi(u1.y);
        c0 += bflo(u2.x); c1 += bfhi(u2.x); c2 += bflo(u2.y); c3 += bfhi(u2.y);
        d0 += bflo(u3.x); d1 += bfhi(u3.x); d2 += bflo(u3.y); d3 += bfhi(u3.y);
    }
    for (; e < end; ++e) {
        const uint2 u = *(const uint2*)(acat2 + (size_t)csr_src[e] * 256 + 128 + lane * 2);
        a0 += bflo(u.x); a1 += bfhi(u.x); a2 += bflo(u.y); a3 += bfhi(u.y);
    }
    a0 += b0 + c0 + d0; a1 += b1 + c1 + d1;
    a2 += b2 + c2 + d2; a3 += b3 + c3 + d3;
    float inv = 1.0f / fmaxf((float)(end - beg), 1.0f);
    uint2 o;
    o.x = pack2(a0 * inv, a1 * inv);
    o.y = pack2(a2 * inv, a3 * inv);
    *(uint2*)(acat2 + (size_t)node * 256 + lane * 2) = o;
}

// stage one 16KB kt-tile: 256 threads x 16B x 4
#define STAGE_KT(kt_, buf_)                                                     \
    {                                                                           \
        const char* s_ = bsrc + (size_t)(kt_) * 16384;                          \
        char* d_ = (char*)&bbuf[buf_][0][0];                                    \
        _Pragma("unroll")                                                       \
        for (int i_ = 0; i_ < 4; ++i_)                                          \
            stage16(s_ + i_ * 4096 + tid * 16, d_ + i_ * 4096 + tid * 16);      \
    }

// ---------------------------------------------------------------------------
// GEMM1: h1 = relu(LN(Acat1[N,256] @ W1 + bl)) -> bf16 into Acat2 cols 256..511
// r7/r14 structure: 64 rows/block, 2x16KB LDS double-buffer, per-kt
// __syncthreads (race-free: drains vmcnt+lgkmcnt per wave before barrier).
// ---------------------------------------------------------------------------
__global__ __launch_bounds__(256, 3)
void gemm1_kernel(const short8v* __restrict__ A,     // Acat1: 32 frags per row
                  const unsigned short* __restrict__ Bpk,  // Wpk1: 8 kt * 16KB
                  const float* __restrict__ bl, const float* __restrict__ g,
                  const float* __restrict__ be,
                  unsigned short* __restrict__ h1out, // Acat2 ushort view, stride 512
                  int N)
{
    __shared__ short8v bbuf[2][16][64];               // 2 x 16KB
    const int tid  = threadIdx.x;
    const int lane = tid & 63;
    const int wave = tid >> 6;
    const int rbase = blockIdx.x * 64 + wave * 16;
    int arow = rbase + (lane & 15);
    if (arow >= N) arow = N - 1;
    const short8v* Ar = A + (size_t)arow * 32 + (lane >> 4);
    const char* bsrc = (const char*)Bpk;

    f32x4 acc[16];
#pragma unroll
    for (int nt = 0; nt < 16; ++nt) acc[nt] = (f32x4){0.f, 0.f, 0.f, 0.f};

    // prologue: stage kt=0
    STAGE_KT(0, 0);
    __syncthreads();

    short8v a = Ar[0];
    int cur = 0;
    for (int kt = 0; kt < 8; ++kt) {
        short8v an = (kt < 7) ? Ar[(kt + 1) * 4] : a;     // A one kt ahead
        if (kt + 1 < 8) {
            STAGE_KT(kt + 1, cur ^ 1);
        }
#pragma unroll
        for (int nt = 0; nt < 16; ++nt)
            acc[nt] = __builtin_amdgcn_mfma_f32_16x16x32_bf16(a, bbuf[cur][nt][lane], acc[nt], 0, 0, 0);
        __syncthreads();
        cur ^= 1;
        a = an;
    }

    // epilogue: bias, wave-local LN (16-lane groups), relu, bf16 store
    const int col0 = lane & 15;
    const int grp  = lane >> 4;
    float s[4] = {0,0,0,0}, ss[4] = {0,0,0,0};
#pragma unroll
    for (int nt = 0; nt < 16; ++nt) {
        float blv = bl[nt * 16 + col0];
#pragma unroll
        for (int r = 0; r < 4; ++r) {
            float v = acc[nt][r] + blv;
            acc[nt][r] = v;
            s[r] += v; ss[r] += v * v;
        }
    }
#pragma unroll
    for (int off = 1; off < 16; off <<= 1) {
#pragma unroll
        for (int r = 0; r < 4; ++r) {
            s[r]  += __shfl_xor(s[r],  off);
            ss[r] += __shfl_xor(ss[r], off);
        }
    }
    float mu[4], inv[4];
#pragma unroll
    for (int r = 0; r < 4; ++r) {
        mu[r] = s[r] * (1.f / 256.f);
        float var = ss[r] * (1.f / 256.f) - mu[r] * mu[r];
        inv[r] = rsqrtf(var + LN_EPS);
    }
#pragma unroll
    for (int nt = 0; nt < 16; ++nt) {
        int col = nt * 16 + col0;
        float gv = g[col], bv = be[col];
#pragma unroll
        for (int r = 0; r < 4; ++r) {
            int srow = rbase + grp * 4 + r;
            if (srow < N) {
                float v = (acc[nt][r] - mu[r]) * inv[r] * gv + bv;
                h1out[(size_t)srow * 512 + 256 + col] = f2bf(fmaxf(v, 0.f));
            }
        }
    }
}

// ---------------------------------------------------------------------------
// GEMM2: out = relu(LN(Acat2[N,512] @ W2 + bl2)) + (x_bf @ Wres + bres)
// r7/r14 structure: 20 kt; in-register LN->relu transform between kt 15 and
// 16, residual GEMM (kt 16..19) accumulates on top via MFMA C-in.
// ---------------------------------------------------------------------------
__global__ __launch_bounds__(256, 2)
void gemm2_kernel(const short8v* __restrict__ A2,    // Acat2: 64 frags per row
                  const short8v* __restrict__ A1,    // Acat1: 32 frags per row
                  const unsigned short* __restrict__ Bpk,  // Wpk2: 20 kt * 16KB
                  const float* __restrict__ bl, const float* __restrict__ g,
                  const float* __restrict__ be, const float* __restrict__ bres,
                  float* __restrict__ out, int N)
{
    __shared__ short8v bbuf[2][16][64];               // 2 x 16KB
    const int tid  = threadIdx.x;
    const int lane = tid & 63;
    const int wave = tid >> 6;
    const int rbase = blockIdx.x * 64 + wave * 16;
    int arow = rbase + (lane & 15);
    if (arow >= N) arow = N - 1;
    const short8v* Ar2 = A2 + (size_t)arow * 64 + (lane >> 4);
    const short8v* Ar1 = A1 + (size_t)arow * 32 + 16 + (lane >> 4);
    const char* bsrc = (const char*)Bpk;

    f32x4 accs[16];
#pragma unroll
    for (int nt = 0; nt < 16; ++nt) accs[nt] = (f32x4){0.f, 0.f, 0.f, 0.f};

    // prologue: stage kt=0
    STAGE_KT(0, 0);
    __syncthreads();

    short8v a = Ar2[0];
    int cur = 0;
    for (int kt = 0; kt < 16; ++kt) {
        short8v an = (kt < 15) ? Ar2[(kt + 1) * 4] : Ar1[0];
        STAGE_KT(kt + 1, cur ^ 1);
#pragma unroll
        for (int nt = 0; nt < 16; ++nt)
            accs[nt] = __builtin_amdgcn_mfma_f32_16x16x32_bf16(a, bbuf[cur][nt][lane], accs[nt], 0, 0, 0);
        __syncthreads();
        cur ^= 1;
        a = an;
    }

    // in-place: accs <- relu(LN(accs + bl))   (wave-local, register-only)
    const int col0 = lane & 15;
    const int grp  = lane >> 4;
    {
        float s[4] = {0,0,0,0}, ss[4] = {0,0,0,0};
#pragma unroll
        for (int nt = 0; nt < 16; ++nt) {
            float blv = bl[nt * 16 + col0];
#pragma unroll
            for (int r = 0; r < 4; ++r) {
                float v = accs[nt][r] + blv;
                accs[nt][r] = v;
                s[r] += v; ss[r] += v * v;
            }
        }
#pragma unroll
        for (int off = 1; off < 16; off <<= 1) {
#pragma unroll
            for (int r = 0; r < 4; ++r) {
                s[r]  += __shfl_xor(s[r],  off);
                ss[r] += __shfl_xor(ss[r], off);
            }
        }
        float mu[4], inv[4];
#pragma unroll
        for (int r = 0; r < 4; ++r) {
            mu[r] = s[r] * (1.f / 256.f);
            float var = ss[r] * (1.f / 256.f) - mu[r] * mu[r];
            inv[r] = rsqrtf(var + LN_EPS);
        }
#pragma unroll
        for (int nt = 0; nt < 16; ++nt) {
            int col = nt * 16 + col0;
            float gv = g[col], bv = be[col];
#pragma unroll
            for (int r = 0; r < 4; ++r) {
                float v = (accs[nt][r] - mu[r]) * inv[r] * gv + bv;
                accs[nt][r] = fmaxf(v, 0.f);
            }
        }
    }

    // residual GEMM kt 16..19 accumulates on top of relu(LN(.))
    for (int kt = 16; kt < 20; ++kt) {
        short8v an = (kt < 19) ? Ar1[(kt - 15) * 4] : a;
        if (kt + 1 < 20) {
            STAGE_KT(kt + 1, cur ^ 1);
        }
#pragma unroll
        for (int nt = 0; nt < 16; ++nt)
            accs[nt] = __builtin_amdgcn_mfma_f32_16x16x32_bf16(a, bbuf[cur][nt][lane], accs[nt], 0, 0, 0);
        __syncthreads();
        cur ^= 1;
        a = an;
    }

#pragma unroll
    for (int nt = 0; nt < 16; ++nt) {
        int col = nt * 16 + col0;
        float brv = bres[col];
#pragma unroll
        for (int r = 0; r < 4; ++r) {
            int srow = rbase + grp * 4 + r;
            if (srow < N)
                out[(size_t)srow * 256 + col] = accs[nt][r] + brv;
        }
    }
}

extern "C" void kernel_launch(void* const* d_in, const int* in_sizes, int n_in,
                              void* d_out, int out_size, void* d_ws, size_t ws_size,
                              hipStream_t stream)
{
    const float* x    = (const float*)d_in[0];
    const int*   ei   = (const int*)d_in[1];
    const float* Wl1  = (const float*)d_in[2];
    const float* bl1  = (const float*)d_in[3];
    const float* Wr1  = (const float*)d_in[4];
    const float* g1   = (const float*)d_in[5];
    const float* be1  = (const float*)d_in[6];
    const float* Wl2  = (const float*)d_in[7];
    const float* bl2  = (const float*)d_in[8];
    const float* Wr2  = (const float*)d_in[9];
    const float* g2   = (const float*)d_in[10];
    const float* be2  = (const float*)d_in[11];
    const float* Wres = (const float*)d_in[12];
    const float* bres = (const float*)d_in[13];

    const int N = in_sizes[0] / 128;
    const int E = in_sizes[1] / 2;
    const int* src = ei;
    const int* dst = ei + E;

    // ws layout: Acat1 N*256 bf16 | Acat2 N*512 bf16 | Wpk1 256*256 bf16
    //            | Wpk2 640*256 bf16 | deg N | row_ptr N+1 | offs N | csr_src E
    //            | blk_sum 256 | blk_pref 256
    unsigned short* acat1 = (unsigned short*)d_ws;
    unsigned short* acat2 = acat1 + (size_t)N * 256;
    unsigned short* wpk1  = acat2 + (size_t)N * 512;
    unsigned short* wpk2  = wpk1 + 256 * 256;
    int* deg      = (int*)(wpk2 + 640 * 256);
    int* row_ptr  = deg + N;
    int* offs     = row_ptr + (N + 1);
    int* csr_src  = offs + N;
    int* blk_sum  = csr_src + E;
    int* blk_pref = blk_sum + 256;

    hipMemsetAsync(deg, 0, (size_t)N * sizeof(int), stream);

    const int eb = (E + 255) / 256;
    const int sb = (N + 1023) / 1024;
    degree_kernel<<<eb, 256, 0, stream>>>(dst, deg, E);
    scan_local_kernel<<<sb, 256, 0, stream>>>(deg, row_ptr, blk_sum, N);
    scan_block_kernel<<<1, 256, 0, stream>>>(blk_sum, blk_pref, row_ptr + N, sb);
    scan_add_kernel<<<sb, 256, 0, stream>>>(row_ptr, offs, blk_pref, N);
    csr_fill_kernel<<<eb, 256, 0, stream>>>(src, dst, offs, csr_src, E);

    prep_x_kernel<<<(N * 64 + 255) / 256, 256, 0, stream>>>(x, (unsigned*)acat1, N);
    pack_w_kernel<<<(8 * 16 * 64 + 255) / 256, 256, 0, stream>>>(Wl1, 128, Wr1, 256, Wr1, wpk1, 256);
    pack_w_kernel<<<(20 * 16 * 64 + 255) / 256, 256, 0, stream>>>(Wl2, 256, Wr2, 512, Wres, wpk2, 640);

    gather1_kernel<<<(N + 3) / 4, 256, 0, stream>>>(row_ptr, csr_src, (unsigned*)acat1, N);

    const int gb = (N + 63) / 64;
    gemm1_kernel<<<gb, 256, 0, stream>>>((const short8v*)acat1, wpk1,
                                         bl1, g1, be1, acat2, N);

    gather2_kernel<<<(N + 3) / 4, 256, 0, stream>>>(row_ptr, csr_src, (unsigned*)acat2, N);

    gemm2_kernel<<<gb, 256, 0, stream>>>((const short8v*)acat2, (const short8v*)acat1,
                                         wpk2, bl2, g2, be2, bres,
                                         (float*)d_out, N);
}

// Round 19
// 275.463 us; speedup vs baseline: 1.1138x; 1.0203x over previous
//
#include <hip/hip_runtime.h>

typedef short short8v __attribute__((ext_vector_type(8)));   // 8 bf16 (4 VGPRs)
typedef float f32x4  __attribute__((ext_vector_type(4)));    // MFMA acc

constexpr float LN_EPS = 1e-5f;

__device__ inline unsigned short f2bf(float f) {
    unsigned u = __float_as_uint(f);
    u += 0x7fffu + ((u >> 16) & 1u);          // RTN-even
    return (unsigned short)(u >> 16);
}
__device__ inline unsigned pack2(float lo, float hi) {
    return (unsigned)f2bf(lo) | ((unsigned)f2bf(hi) << 16);
}
__device__ inline float bflo(unsigned u) { return __uint_as_float(u << 16); }
__device__ inline float bfhi(unsigned u) { return __uint_as_float(u & 0xffff0000u); }

// async global->LDS, 16B per lane (dest = wave-uniform base + lane*16)
__device__ inline void stage16(const void* gsrc, void* ldst) {
    __builtin_amdgcn_global_load_lds(
        (const __attribute__((address_space(1))) unsigned int*)gsrc,
        (__attribute__((address_space(3))) unsigned int*)ldst,
        16, 0, 0);
}

// ---------------------------------------------------------------------------
// CSR build: degree -> 3-phase device-wide exclusive scan -> bucket fill
// ---------------------------------------------------------------------------
__global__ __launch_bounds__(256)
void degree_kernel(const int* __restrict__ dst, int* __restrict__ deg, int E)
{
    int e = blockIdx.x * 256 + threadIdx.x;
    if (e < E) atomicAdd(&deg[dst[e]], 1);
}

__global__ __launch_bounds__(256)
void scan_local_kernel(const int* __restrict__ deg, int* __restrict__ local,
                       int* __restrict__ blk_sum, int N)
{
    __shared__ int tmp[256];
    const int tid = threadIdx.x;
    const int base = blockIdx.x * 1024 + tid * 4;
    int v0 = (base + 0 < N) ? deg[base + 0] : 0;
    int v1 = (base + 1 < N) ? deg[base + 1] : 0;
    int v2 = (base + 2 < N) ? deg[base + 2] : 0;
    int v3 = (base + 3 < N) ? deg[base + 3] : 0;
    const int s = v0 + v1 + v2 + v3;
    tmp[tid] = s;
    __syncthreads();
    for (int off = 1; off < 256; off <<= 1) {
        int t = (tid >= off) ? tmp[tid - off] : 0;
        __syncthreads();
        tmp[tid] += t;
        __syncthreads();
    }
    int run = tmp[tid] - s;
    if (base + 0 < N) local[base + 0] = run;  run += v0;
    if (base + 1 < N) local[base + 1] = run;  run += v1;
    if (base + 2 < N) local[base + 2] = run;  run += v2;
    if (base + 3 < N) local[base + 3] = run;
    if (tid == 255) blk_sum[blockIdx.x] = tmp[255];
}

__global__ __launch_bounds__(256)
void scan_block_kernel(const int* __restrict__ blk_sum, int* __restrict__ blk_pref,
                       int* __restrict__ total_out, int B)
{
    __shared__ int tmp[256];
    const int tid = threadIdx.x;
    int v = (tid < B) ? blk_sum[tid] : 0;
    tmp[tid] = v;
    __syncthreads();
    for (int off = 1; off < 256; off <<= 1) {
        int t = (tid >= off) ? tmp[tid - off] : 0;
        __syncthreads();
        tmp[tid] += t;
        __syncthreads();
    }
    if (tid < B) blk_pref[tid] = tmp[tid] - v;
    if (tid == 255) *total_out = tmp[255];
}

__global__ __launch_bounds__(256)
void scan_add_kernel(int* __restrict__ row_ptr, int* __restrict__ offs,
                     const int* __restrict__ blk_pref, int N)
{
    const int base = blockIdx.x * 1024 + threadIdx.x * 4;
    const int p = blk_pref[blockIdx.x];
#pragma unroll
    for (int i = 0; i < 4; ++i) {
        int idx = base + i;
        if (idx < N) {
            int val = row_ptr[idx] + p;
            row_ptr[idx] = val;
            offs[idx] = val;
        }
    }
}

__global__ __launch_bounds__(256)
void csr_fill_kernel(const int* __restrict__ src, const int* __restrict__ dst,
                     int* __restrict__ offs, int* __restrict__ csr_src, int E)
{
    int e = blockIdx.x * 256 + threadIdx.x;
    if (e < E) {
        int p = atomicAdd(&offs[dst[e]], 1);
        csr_src[p] = src[e];
    }
}

// ---------------------------------------------------------------------------
// x fp32 -> bf16 into Acat1 cols 128..255
// ---------------------------------------------------------------------------
__global__ __launch_bounds__(256)
void prep_x_kernel(const float* __restrict__ x, unsigned* __restrict__ acat1, int N)
{
    int t = blockIdx.x * 256 + threadIdx.x;
    if (t >= N * 64) return;
    int row = t >> 6, c = t & 63;
    float2 v = ((const float2*)x)[t];
    acat1[(size_t)row * 128 + 64 + c] = pack2(v.x, v.y);
}

// ---------------------------------------------------------------------------
// Pack fp32 weights into MFMA B-fragment layout.
// frag (kt,nt): lane l holds col j = nt*16+(l&15), k = kt*32+(l>>4)*8+e.
// ---------------------------------------------------------------------------
__global__ __launch_bounds__(256)
void pack_w_kernel(const float* __restrict__ WA, int ka,
                   const float* __restrict__ WB, int kb,
                   const float* __restrict__ WC,
                   unsigned short* __restrict__ out, int K)
{
    int t = blockIdx.x * 256 + threadIdx.x;
    int total = (K / 32) * 16 * 64;
    if (t >= total) return;
    int lane = t & 63;
    int nt = (t >> 6) & 15;
    int kt = t >> 10;
    int j = nt * 16 + (lane & 15);
    unsigned short* o = out + (size_t)t * 8;
#pragma unroll
    for (int e = 0; e < 8; ++e) {
        int k = kt * 32 + ((lane >> 4) & 3) * 8 + e;
        float v;
        if (k < ka)      v = WA[(size_t)k * 256 + j];
        else if (k < kb) v = WB[(size_t)(k - ka) * 256 + j];
        else             v = WC[(size_t)(k - kb) * 256 + j];
        o[e] = f2bf(v);
    }
}

// ---------------------------------------------------------------------------
// Gather-mean of x_bf -> Acat1 cols 0..127. Wave/node, 8-way edge unroll.
// ---------------------------------------------------------------------------
__global__ __launch_bounds__(256)
void gather1_kernel(const int* __restrict__ row_ptr, const int* __restrict__ csr_src,
                    unsigned* __restrict__ acat1, int N)
{
    int node = blockIdx.x * 4 + (threadIdx.x >> 6);
    int lane = threadIdx.x & 63;
    if (node >= N) return;
    int beg = row_ptr[node], end = row_ptr[node + 1];
    float a0 = 0.f, a1 = 0.f, b0 = 0.f, b1 = 0.f;
    float c0 = 0.f, c1 = 0.f, d0 = 0.f, d1 = 0.f;
    int e = beg;
    for (; e + 7 < end; e += 8) {
        unsigned u0 = acat1[(size_t)csr_src[e + 0] * 128 + 64 + lane];
        unsigned u1 = acat1[(size_t)csr_src[e + 1] * 128 + 64 + lane];
        unsigned u2 = acat1[(size_t)csr_src[e + 2] * 128 + 64 + lane];
        unsigned u3 = acat1[(size_t)csr_src[e + 3] * 128 + 64 + lane];
        unsigned u4 = acat1[(size_t)csr_src[e + 4] * 128 + 64 + lane];
        unsigned u5 = acat1[(size_t)csr_src[e + 5] * 128 + 64 + lane];
        unsigned u6 = acat1[(size_t)csr_src[e + 6] * 128 + 64 + lane];
        unsigned u7 = acat1[(size_t)csr_src[e + 7] * 128 + 64 + lane];
        a0 += bflo(u0); a1 += bfhi(u0);
        b0 += bflo(u1); b1 += bfhi(u1);
        c0 += bflo(u2); c1 += bfhi(u2);
        d0 += bflo(u3); d1 += bfhi(u3);
        a0 += bflo(u4); a1 += bfhi(u4);
        b0 += bflo(u5); b1 += bfhi(u5);
        c0 += bflo(u6); c1 += bfhi(u6);
        d0 += bflo(u7); d1 += bfhi(u7);
    }
    for (; e + 3 < end; e += 4) {
        unsigned u0 = acat1[(size_t)csr_src[e + 0] * 128 + 64 + lane];
        unsigned u1 = acat1[(size_t)csr_src[e + 1] * 128 + 64 + lane];
        unsigned u2 = acat1[(size_t)csr_src[e + 2] * 128 + 64 + lane];
        unsigned u3 = acat1[(size_t)csr_src[e + 3] * 128 + 64 + lane];
        a0 += bflo(u0); a1 += bfhi(u0);
        b0 += bflo(u1); b1 += bfhi(u1);
        c0 += bflo(u2); c1 += bfhi(u2);
        d0 += bflo(u3); d1 += bfhi(u3);
    }
    for (; e < end; ++e) {
        unsigned u = acat1[(size_t)csr_src[e] * 128 + 64 + lane];
        a0 += bflo(u); a1 += bfhi(u);
    }
    a0 += b0 + c0 + d0; a1 += b1 + c1 + d1;
    float inv = 1.0f / fmaxf((float)(end - beg), 1.0f);
    acat1[(size_t)node * 128 + lane] = pack2(a0 * inv, a1 * inv);
}

// ---------------------------------------------------------------------------
// Gather-mean of h1_bf -> Acat2 cols 0..255. Wave/node, uint2, 8-way unroll.
// ---------------------------------------------------------------------------
__global__ __launch_bounds__(256)
void gather2_kernel(const int* __restrict__ row_ptr, const int* __restrict__ csr_src,
                    unsigned* __restrict__ acat2, int N)
{
    int node = blockIdx.x * 4 + (threadIdx.x >> 6);
    int lane = threadIdx.x & 63;
    if (node >= N) return;
    int beg = row_ptr[node], end = row_ptr[node + 1];
    float a0 = 0.f, a1 = 0.f, a2 = 0.f, a3 = 0.f;
    float b0 = 0.f, b1 = 0.f, b2 = 0.f, b3 = 0.f;
    float c0 = 0.f, c1 = 0.f, c2 = 0.f, c3 = 0.f;
    float d0 = 0.f, d1 = 0.f, d2 = 0.f, d3 = 0.f;
    int e = beg;
    for (; e + 7 < end; e += 8) {
        const uint2 u0 = *(const uint2*)(acat2 + (size_t)csr_src[e + 0] * 256 + 128 + lane * 2);
        const uint2 u1 = *(const uint2*)(acat2 + (size_t)csr_src[e + 1] * 256 + 128 + lane * 2);
        const uint2 u2 = *(const uint2*)(acat2 + (size_t)csr_src[e + 2] * 256 + 128 + lane * 2);
        const uint2 u3 = *(const uint2*)(acat2 + (size_t)csr_src[e + 3] * 256 + 128 + lane * 2);
        const uint2 u4 = *(const uint2*)(acat2 + (size_t)csr_src[e + 4] * 256 + 128 + lane * 2);
        const uint2 u5 = *(const uint2*)(acat2 + (size_t)csr_src[e + 5] * 256 + 128 + lane * 2);
        const uint2 u6 = *(const uint2*)(acat2 + (size_t)csr_src[e + 6] * 256 + 128 + lane * 2);
        const uint2 u7 = *(const uint2*)(acat2 + (size_t)csr_src[e + 7] * 256 + 128 + lane * 2);
        a0 += bflo(u0.x); a1 += bfhi(u0.x); a2 += bflo(u0.y); a3 += bfhi(u0.y);
        b0 += bflo(u1.x); b1 += bfhi(u1.x); b2 += bflo(u1.y); b3 += bfhi(u1.y);
        c0 += bflo(u2.x); c1 += bfhi(u2.x); c2 += bflo(u2.y); c3 += bfhi(u2.y);
        d0 += bflo(u3.x); d1 += bfhi(u3.x); d2 += bflo(u3.y); d3 += bfhi(u3.y);
        a0 += bflo(u4.x); a1 += bfhi(u4.x); a2 += bflo(u4.y); a3 += bfhi(u4.y);
        b0 += bflo(u5.x); b1 += bfhi(u5.x); b2 += bflo(u5.y); b3 += bfhi(u5.y);
        c0 += bflo(u6.x); c1 += bfhi(u6.x); c2 += bflo(u6.y); c3 += bfhi(u6.y);
        d0 += bflo(u7.x); d1 += bfhi(u7.x); d2 += bflo(u7.y); d3 += bfhi(u7.y);
    }
    for (; e + 3 < end; e += 4) {
        const uint2 u0 = *(const uint2*)(acat2 + (size_t)csr_src[e + 0] * 256 + 128 + lane * 2);
        const uint2 u1 = *(const uint2*)(acat2 + (size_t)csr_src[e + 1] * 256 + 128 + lane * 2);
        const uint2 u2 = *(const uint2*)(acat2 + (size_t)csr_src[e + 2] * 256 + 128 + lane * 2);
        const uint2 u3 = *(const uint2*)(acat2 + (size_t)csr_src[e + 3] * 256 + 128 + lane * 2);
        a0 += bflo(u0.x); a1 += bfhi(u0.x); a2 += bflo(u0.y); a3 += bfhi(u0.y);
        b0 += bflo(u1.x); b1 += bfhi(u1.x); b2 += bflo(u1.y); b3 += bfhi(u1.y);
        c0 += bflo(u2.x); c1 += bfhi(u2.x); c2 += bflo(u2.y); c3 += bfhi(u2.y);
        d0 += bflo(u3.x); d1 += bfhi(u3.x); d2 += bflo(u3.y); d3 += bfhi(u3.y);
    }
    for (; e < end; ++e) {
        const uint2 u = *(const uint2*)(acat2 + (size_t)csr_src[e] * 256 + 128 + lane * 2);
        a0 += bflo(u.x); a1 += bfhi(u.x); a2 += bflo(u.y); a3 += bfhi(u.y);
    }
    a0 += b0 + c0 + d0; a1 += b1 + c1 + d1;
    a2 += b2 + c2 + d2; a3 += b3 + c3 + d3;
    float inv = 1.0f / fmaxf((float)(end - beg), 1.0f);
    uint2 o;
    o.x = pack2(a0 * inv, a1 * inv);
    o.y = pack2(a2 * inv, a3 * inv);
    *(uint2*)(acat2 + (size_t)node * 256 + lane * 2) = o;
}

// stage one 16KB kt-tile into bbuf[buf_]: 256 threads x 16B x 4
#define STAGE_KT(kt_, buf_)                                                     \
    {                                                                           \
        const char* s_ = bsrc + (size_t)(kt_) * 16384;                          \
        char* d_ = (char*)&bbuf[buf_][0][0];                                    \
        _Pragma("unroll")                                                       \
        for (int i_ = 0; i_ < 4; ++i_)                                          \
            stage16(s_ + i_ * 4096 + tid * 16, d_ + i_ * 4096 + tid * 16);      \
    }

// stage one 32KB kt-PAIR (kts 2p, 2p+1) into pbuf[buf_]: 256 thr x 16B x 8
#define STAGE_PAIR(p_, buf_)                                                    \
    {                                                                           \
        const char* s_ = bsrc + (size_t)(p_) * 32768;                           \
        char* d_ = (char*)&pbuf[buf_][0][0][0];                                 \
        _Pragma("unroll")                                                       \
        for (int i_ = 0; i_ < 8; ++i_)                                          \
            stage16(s_ + i_ * 4096 + tid * 16, d_ + i_ * 4096 + tid * 16);      \
    }

// ---------------------------------------------------------------------------
// GEMM1: h1 = relu(LN(Acat1[N,256] @ W1 + bl)) -> bf16 into Acat2 cols 256..511
// r18 verbatim: 64 rows/block, 2x16KB LDS double-buffer, per-kt __syncthreads.
// ---------------------------------------------------------------------------
__global__ __launch_bounds__(256, 3)
void gemm1_kernel(const short8v* __restrict__ A,     // Acat1: 32 frags per row
                  const unsigned short* __restrict__ Bpk,  // Wpk1: 8 kt * 16KB
                  const float* __restrict__ bl, const float* __restrict__ g,
                  const float* __restrict__ be,
                  unsigned short* __restrict__ h1out, // Acat2 ushort view, stride 512
                  int N)
{
    __shared__ short8v bbuf[2][16][64];               // 2 x 16KB
    const int tid  = threadIdx.x;
    const int lane = tid & 63;
    const int wave = tid >> 6;
    const int rbase = blockIdx.x * 64 + wave * 16;
    int arow = rbase + (lane & 15);
    if (arow >= N) arow = N - 1;
    const short8v* Ar = A + (size_t)arow * 32 + (lane >> 4);
    const char* bsrc = (const char*)Bpk;

    f32x4 acc[16];
#pragma unroll
    for (int nt = 0; nt < 16; ++nt) acc[nt] = (f32x4){0.f, 0.f, 0.f, 0.f};

    STAGE_KT(0, 0);
    __syncthreads();

    short8v a = Ar[0];
    int cur = 0;
    for (int kt = 0; kt < 8; ++kt) {
        short8v an = (kt < 7) ? Ar[(kt + 1) * 4] : a;
        if (kt + 1 < 8) {
            STAGE_KT(kt + 1, cur ^ 1);
        }
#pragma unroll
        for (int nt = 0; nt < 16; ++nt)
            acc[nt] = __builtin_amdgcn_mfma_f32_16x16x32_bf16(a, bbuf[cur][nt][lane], acc[nt], 0, 0, 0);
        __syncthreads();
        cur ^= 1;
        a = an;
    }

    const int col0 = lane & 15;
    const int grp  = lane >> 4;
    float s[4] = {0,0,0,0}, ss[4] = {0,0,0,0};
#pragma unroll
    for (int nt = 0; nt < 16; ++nt) {
        float blv = bl[nt * 16 + col0];
#pragma unroll
        for (int r = 0; r < 4; ++r) {
            float v = acc[nt][r] + blv;
            acc[nt][r] = v;
            s[r] += v; ss[r] += v * v;
        }
    }
#pragma unroll
    for (int off = 1; off < 16; off <<= 1) {
#pragma unroll
        for (int r = 0; r < 4; ++r) {
            s[r]  += __shfl_xor(s[r],  off);
            ss[r] += __shfl_xor(ss[r], off);
        }
    }
    float mu[4], inv[4];
#pragma unroll
    for (int r = 0; r < 4; ++r) {
        mu[r] = s[r] * (1.f / 256.f);
        float var = ss[r] * (1.f / 256.f) - mu[r] * mu[r];
        inv[r] = rsqrtf(var + LN_EPS);
    }
#pragma unroll
    for (int nt = 0; nt < 16; ++nt) {
        int col = nt * 16 + col0;
        float gv = g[col], bv = be[col];
#pragma unroll
        for (int r = 0; r < 4; ++r) {
            int srow = rbase + grp * 4 + r;
            if (srow < N) {
                float v = (acc[nt][r] - mu[r]) * inv[r] * gv + bv;
                h1out[(size_t)srow * 512 + 256 + col] = f2bf(fmaxf(v, 0.f));
            }
        }
    }
}

// ---------------------------------------------------------------------------
// GEMM2: out = relu(LN(Acat2[N,512] @ W2 + bl2)) + (x_bf @ Wres + bres)
// PAIR-staged: 2 kts per __syncthreads (10 barriers instead of 20), 2x32KB
// buffers. Same sync semantics as r18 (pure syncthreads double-buffer).
// LN->relu between pair 7 (kt15) and pair 8 (kt16); residual accumulates
// via MFMA C-in.
// ---------------------------------------------------------------------------
__global__ __launch_bounds__(256, 2)
void gemm2_kernel(const short8v* __restrict__ A2,    // Acat2: 64 frags per row
                  const short8v* __restrict__ A1,    // Acat1: 32 frags per row
                  const unsigned short* __restrict__ Bpk,  // Wpk2: 20 kt * 16KB
                  const float* __restrict__ bl, const float* __restrict__ g,
                  const float* __restrict__ be, const float* __restrict__ bres,
                  float* __restrict__ out, int N)
{
    __shared__ short8v pbuf[2][2][16][64];            // 2 x 32KB (kt-pair tiles)
    const int tid  = threadIdx.x;
    const int lane = tid & 63;
    const int wave = tid >> 6;
    const int rbase = blockIdx.x * 64 + wave * 16;
    int arow = rbase + (lane & 15);
    if (arow >= N) arow = N - 1;
    const short8v* Ar2 = A2 + (size_t)arow * 64 + (lane >> 4);
    const short8v* Ar1 = A1 + (size_t)arow * 32 + 16 + (lane >> 4);
    const char* bsrc = (const char*)Bpk;

    f32x4 accs[16];
#pragma unroll
    for (int nt = 0; nt < 16; ++nt) accs[nt] = (f32x4){0.f, 0.f, 0.f, 0.f};

    const int col0 = lane & 15;
    const int grp  = lane >> 4;

    STAGE_PAIR(0, 0);
    short8v a0 = Ar2[0], a1 = Ar2[4];
    __syncthreads();

    int cur = 0;
    for (int p = 0; p < 10; ++p) {
        short8v an0 = a0, an1 = a1;
        if (p + 1 < 10) {
            STAGE_PAIR(p + 1, cur ^ 1);
            const int k0 = 2 * p + 2, k1 = 2 * p + 3;
            an0 = (k0 < 16) ? Ar2[k0 * 4] : Ar1[(k0 - 16) * 4];
            an1 = (k1 < 16) ? Ar2[k1 * 4] : Ar1[(k1 - 16) * 4];
        }

        if (p == 8) {
            // accs holds kts 0..15; apply relu(LN(.+bl)) before residual kts
            float s[4] = {0,0,0,0}, ss[4] = {0,0,0,0};
#pragma unroll
            for (int nt = 0; nt < 16; ++nt) {
                float blv = bl[nt * 16 + col0];
#pragma unroll
                for (int r = 0; r < 4; ++r) {
                    float v = accs[nt][r] + blv;
                    accs[nt][r] = v;
                    s[r] += v; ss[r] += v * v;
                }
            }
#pragma unroll
            for (int off = 1; off < 16; off <<= 1) {
#pragma unroll
                for (int r = 0; r < 4; ++r) {
                    s[r]  += __shfl_xor(s[r],  off);
                    ss[r] += __shfl_xor(ss[r], off);
                }
            }
#pragma unroll
            for (int r = 0; r < 4; ++r) {
                float mu = s[r] * (1.f / 256.f);
                float var = ss[r] * (1.f / 256.f) - mu * mu;
                float invs = rsqrtf(var + LN_EPS);
#pragma unroll
                for (int nt = 0; nt < 16; ++nt) {
                    int col = nt * 16 + col0;
                    float v = (accs[nt][r] - mu) * invs * g[col] + be[col];
                    accs[nt][r] = fmaxf(v, 0.f);
                }
            }
        }

#pragma unroll
        for (int nt = 0; nt < 16; ++nt)
            accs[nt] = __builtin_amdgcn_mfma_f32_16x16x32_bf16(a0, pbuf[cur][0][nt][lane], accs[nt], 0, 0, 0);
#pragma unroll
        for (int nt = 0; nt < 16; ++nt)
            accs[nt] = __builtin_amdgcn_mfma_f32_16x16x32_bf16(a1, pbuf[cur][1][nt][lane], accs[nt], 0, 0, 0);
        __syncthreads();
        cur ^= 1;
        a0 = an0; a1 = an1;
    }

#pragma unroll
    for (int nt = 0; nt < 16; ++nt) {
        int col = nt * 16 + col0;
        float brv = bres[col];
#pragma unroll
        for (int r = 0; r < 4; ++r) {
            int srow = rbase + grp * 4 + r;
            if (srow < N)
                out[(size_t)srow * 256 + col] = accs[nt][r] + brv;
        }
    }
}

extern "C" void kernel_launch(void* const* d_in, const int* in_sizes, int n_in,
                              void* d_out, int out_size, void* d_ws, size_t ws_size,
                              hipStream_t stream)
{
    const float* x    = (const float*)d_in[0];
    const int*   ei   = (const int*)d_in[1];
    const float* Wl1  = (const float*)d_in[2];
    const float* bl1  = (const float*)d_in[3];
    const float* Wr1  = (const float*)d_in[4];
    const float* g1   = (const float*)d_in[5];
    const float* be1  = (const float*)d_in[6];
    const float* Wl2  = (const float*)d_in[7];
    const float* bl2  = (const float*)d_in[8];
    const float* Wr2  = (const float*)d_in[9];
    const float* g2   = (const float*)d_in[10];
    const float* be2  = (const float*)d_in[11];
    const float* Wres = (const float*)d_in[12];
    const float* bres = (const float*)d_in[13];

    const int N = in_sizes[0] / 128;
    const int E = in_sizes[1] / 2;
    const int* src = ei;
    const int* dst = ei + E;

    // ws layout: Acat1 N*256 bf16 | Acat2 N*512 bf16 | Wpk1 256*256 bf16
    //            | Wpk2 640*256 bf16 | deg N | row_ptr N+1 | offs N | csr_src E
    //            | blk_sum 256 | blk_pref 256
    unsigned short* acat1 = (unsigned short*)d_ws;
    unsigned short* acat2 = acat1 + (size_t)N * 256;
    unsigned short* wpk1  = acat2 + (size_t)N * 512;
    unsigned short* wpk2  = wpk1 + 256 * 256;
    int* deg      = (int*)(wpk2 + 640 * 256);
    int* row_ptr  = deg + N;
    int* offs     = row_ptr + (N + 1);
    int* csr_src  = offs + N;
    int* blk_sum  = csr_src + E;
    int* blk_pref = blk_sum + 256;

    hipMemsetAsync(deg, 0, (size_t)N * sizeof(int), stream);

    const int eb = (E + 255) / 256;
    const int sb = (N + 1023) / 1024;
    degree_kernel<<<eb, 256, 0, stream>>>(dst, deg, E);
    scan_local_kernel<<<sb, 256, 0, stream>>>(deg, row_ptr, blk_sum, N);
    scan_block_kernel<<<1, 256, 0, stream>>>(blk_sum, blk_pref, row_ptr + N, sb);
    scan_add_kernel<<<sb, 256, 0, stream>>>(row_ptr, offs, blk_pref, N);
    csr_fill_kernel<<<eb, 256, 0, stream>>>(src, dst, offs, csr_src, E);

    prep_x_kernel<<<(N * 64 + 255) / 256, 256, 0, stream>>>(x, (unsigned*)acat1, N);
    pack_w_kernel<<<(8 * 16 * 64 + 255) / 256, 256, 0, stream>>>(Wl1, 128, Wr1, 256, Wr1, wpk1, 256);
    pack_w_kernel<<<(20 * 16 * 64 + 255) / 256, 256, 0, stream>>>(Wl2, 256, Wr2, 512, Wres, wpk2, 640);

    gather1_kernel<<<(N + 3) / 4, 256, 0, stream>>>(row_ptr, csr_src, (unsigned*)acat1, N);

    const int gb = (N + 63) / 64;
    gemm1_kernel<<<gb, 256, 0, stream>>>((const short8v*)acat1, wpk1,
                                         bl1, g1, be1, acat2, N);

    gather2_kernel<<<(N + 3) / 4, 256, 0, stream>>>(row_ptr, csr_src, (unsigned*)acat2, N);

    gemm2_kernel<<<gb, 256, 0, stream>>>((const short8v*)acat2, (const short8v*)acat1,
                                         wpk2, bl2, g2, be2, bres,
                                         (float*)d_out, N);
}